// Round 5
// baseline (216.893 us; speedup 1.0000x reference)
//
#include <hip/hip_runtime.h>
#include <math.h>

#define NPTS 200
#define NCH  13
#define BLK  256
#define FLT_PER_BATCH (NPTS * NCH)          // 2600
#define F4_PER_BATCH  (FLT_PER_BATCH / 4)   // 650

// ---------------------------------------------------------------------------
// Fully fused: one wave per batch, wave-private LDS, ZERO __syncthreads.
// reduce -> Horn/Jacobi solve (redundant on all 64 lanes) -> apply.
// ---------------------------------------------------------------------------
__global__ __launch_bounds__(BLK) void svd_align_fused(
    const float* __restrict__ net_in,   // (B, 200, 13)
    const float* __restrict__ shift_p,
    const float* __restrict__ a_p,
    const float* __restrict__ b_p,
    float* __restrict__ out)            // (B, 200, 3)
{
    __shared__ float s_in[4 * FLT_PER_BATCH];   // 4 waves * 2600 floats (41.6 KB)
    __shared__ float s_part[4][16][20];         // per-wave 16x16 transpose (5.1 KB)

    const int tid = threadIdx.x;
    const int w   = tid >> 6;                   // wave id = local batch
    const int l   = tid & 63;
    const int b   = blockIdx.x * 4 + w;         // global batch

    const float shift = shift_p[0];
    const float aa    = a_p[0];
    const float bb    = b_p[0];

    // ---- phase 1: stage this wave's batch (650 float4, all in flight) ----
    {
        const float4* src4 = (const float4*)(net_in + (size_t)b * FLT_PER_BATCH);
        float4* dst4 = (float4*)(s_in + w * FLT_PER_BATCH);
        #pragma unroll
        for (int j = 0; j < 10; ++j) dst4[l + 64 * j] = src4[l + 64 * j];
        if (l < 10) dst4[640 + l] = src4[640 + l];
    }
    // wave-synchronous: compiler orders ds/vm waits; no barrier needed.

    // ---- phase 2: per-lane accumulation; keep raw xyz2 in registers ----
    float acc[16];
    #pragma unroll
    for (int k = 0; k < 16; ++k) acc[k] = 0.f;

    float rx[4], ry[4], rz[4];                  // raw xyz2 for the apply phase

    const float* base = s_in + w * FLT_PER_BATCH;
    #pragma unroll
    for (int j = 0; j < 4; ++j) {
        const int p = l + 64 * j;
        if (p < NPTS) {
            const float* q = base + p * NCH;    // stride 13: conflict-free
            float wt = aa * q[0] + bb;
            wt = fmaxf(wt, 0.f) + 1e-8f;
            float x2 = q[4], y2 = q[5], z2 = q[6];
            rx[j] = x2; ry[j] = y2; rz[j] = z2;
            float v1x = fmaf(shift, q[7],  q[1]);
            float v1y = fmaf(shift, q[8],  q[2]);
            float v1z = fmaf(shift, q[9],  q[3]);
            float v2x = fmaf(shift, q[10], x2);
            float v2y = fmaf(shift, q[11], y2);
            float v2z = fmaf(shift, q[12], z2);
            float wv2x = wt * v2x, wv2y = wt * v2y, wv2z = wt * v2z;
            acc[0] += wt;
            acc[1] += wt * v1x; acc[2] += wt * v1y; acc[3] += wt * v1z;
            acc[4] += wv2x;     acc[5] += wv2y;     acc[6] += wv2z;
            acc[7]  += wv2x * v1x; acc[8]  += wv2x * v1y; acc[9]  += wv2x * v1z;
            acc[10] += wv2y * v1x; acc[11] += wv2y * v1y; acc[12] += wv2y * v1z;
            acc[13] += wv2z * v1x; acc[14] += wv2z * v1y; acc[15] += wv2z * v1z;
        } else {
            rx[j] = 0.f; ry[j] = 0.f; rz[j] = 0.f;
        }
    }

    // ---- phase 3: 64 -> 16 lanes via shuffles, then 16x16 LDS transpose ----
    #pragma unroll
    for (int k = 0; k < 16; ++k) {
        acc[k] += __shfl_down(acc[k], 32, 64);
        acc[k] += __shfl_down(acc[k], 16, 64);
    }
    if (l < 16) {
        float4* pp = (float4*)&s_part[w][l][0];
        pp[0] = make_float4(acc[0],  acc[1],  acc[2],  acc[3]);
        pp[1] = make_float4(acc[4],  acc[5],  acc[6],  acc[7]);
        pp[2] = make_float4(acc[8],  acc[9],  acc[10], acc[11]);
        pp[3] = make_float4(acc[12], acc[13], acc[14], acc[15]);
    }
    float tot = 0.f;                      // lane k<16 accumulates total[k]
    {
        const int lk = (l < 16) ? l : 0;
        #pragma unroll
        for (int r = 0; r < 16; ++r) tot += s_part[w][r][lk];
    }
    // broadcast the 16 totals to every lane
    float f[16];
    #pragma unroll
    for (int k = 0; k < 16; ++k) f[k] = __shfl(tot, k, 64);

    // ---- phase 4: Horn quaternion / 4x4 Jacobi, redundant on all lanes ----
    const float W = f[0];
    const float invW = 1.0f / W;
    const float v1cx = f[1] * invW, v1cy = f[2] * invW, v1cz = f[3] * invW;
    const float v2cx = f[4] * invW, v2cy = f[5] * invW, v2cz = f[6] * invW;

    const float Sxx = f[7]  - W * v2cx * v1cx;
    const float Sxy = f[8]  - W * v2cx * v1cy;
    const float Sxz = f[9]  - W * v2cx * v1cz;
    const float Syx = f[10] - W * v2cy * v1cx;
    const float Syy = f[11] - W * v2cy * v1cy;
    const float Syz = f[12] - W * v2cy * v1cz;
    const float Szx = f[13] - W * v2cz * v1cx;
    const float Szy = f[14] - W * v2cz * v1cy;
    const float Szz = f[15] - W * v2cz * v1cz;

    float A[4][4];
    A[0][0] = Sxx + Syy + Szz;
    A[0][1] = Syz - Szy;  A[0][2] = Szx - Sxz;  A[0][3] = Sxy - Syx;
    A[1][1] = Sxx - Syy - Szz;
    A[1][2] = Sxy + Syx;  A[1][3] = Szx + Sxz;
    A[2][2] = -Sxx + Syy - Szz;
    A[2][3] = Syz + Szy;
    A[3][3] = -Sxx - Syy + Szz;
    A[1][0] = A[0][1]; A[2][0] = A[0][2]; A[3][0] = A[0][3];
    A[2][1] = A[1][2]; A[3][1] = A[1][3]; A[3][2] = A[2][3];

    float V[4][4] = {{1,0,0,0},{0,1,0,0},{0,0,1,0},{0,0,0,1}};

    const int prs[6][2] = {{0,1},{0,2},{0,3},{1,2},{1,3},{2,3}};
    for (int sweep = 0; sweep < 6; ++sweep) {
        #pragma unroll
        for (int r = 0; r < 6; ++r) {
            const int p = prs[r][0], q = prs[r][1];
            float apq = A[p][q];
            if (apq != 0.0f) {                  // wave-uniform branch
                float tau = (A[q][q] - A[p][p]) / (2.0f * apq);
                float t = copysignf(1.0f, tau) /
                          (fabsf(tau) + sqrtf(1.0f + tau * tau));
                float c = rsqrtf(1.0f + t * t);
                float s = t * c;
                #pragma unroll
                for (int k = 0; k < 4; ++k) {
                    float a1 = A[p][k], a2 = A[q][k];
                    A[p][k] = c * a1 - s * a2;
                    A[q][k] = s * a1 + c * a2;
                }
                #pragma unroll
                for (int k = 0; k < 4; ++k) {
                    float a1 = A[k][p], a2 = A[k][q];
                    A[k][p] = c * a1 - s * a2;
                    A[k][q] = s * a1 + c * a2;
                }
                #pragma unroll
                for (int k = 0; k < 4; ++k) {
                    float a1 = V[k][p], a2 = V[k][q];
                    V[k][p] = c * a1 - s * a2;
                    V[k][q] = s * a1 + c * a2;
                }
            }
        }
    }

    int best = 0;
    #pragma unroll
    for (int i = 1; i < 4; ++i) if (A[i][i] > A[best][best]) best = i;
    const float q0 = V[0][best], qx = V[1][best], qy = V[2][best], qz = V[3][best];

    const float R00 = q0*q0 + qx*qx - qy*qy - qz*qz;
    const float R01 = 2.0f * (qx*qy - q0*qz);
    const float R02 = 2.0f * (qx*qz + q0*qy);
    const float R10 = 2.0f * (qx*qy + q0*qz);
    const float R11 = q0*q0 - qx*qx + qy*qy - qz*qz;
    const float R12 = 2.0f * (qy*qz - q0*qx);
    const float R20 = 2.0f * (qx*qz - q0*qy);
    const float R21 = 2.0f * (qy*qz + q0*qx);
    const float R22 = q0*q0 - qx*qx - qy*qy + qz*qz;

    const float t0 = v1cx - (R00 * v2cx + R01 * v2cy + R02 * v2cz);
    const float t1 = v1cy - (R10 * v2cx + R11 * v2cy + R12 * v2cz);
    const float t2 = v1cz - (R20 * v2cx + R21 * v2cy + R22 * v2cz);

    // ---- phase 5: apply R,t to the registered xyz2 and store ----
    float* ob = out + (size_t)b * (NPTS * 3);
    #pragma unroll
    for (int j = 0; j < 4; ++j) {
        const int p = l + 64 * j;
        if (p < NPTS) {
            const float x = rx[j], y = ry[j], z = rz[j];
            float* o = ob + p * 3;
            o[0] = R00 * x + R01 * y + R02 * z + t0;
            o[1] = R10 * x + R11 * y + R12 * z + t1;
            o[2] = R20 * x + R21 * y + R22 * z + t2;
        }
    }
}

extern "C" void kernel_launch(void* const* d_in, const int* in_sizes, int n_in,
                              void* d_out, int out_size, void* d_ws, size_t ws_size,
                              hipStream_t stream) {
    const float* net_in  = (const float*)d_in[0];
    const float* shift_p = (const float*)d_in[1];
    const float* a_p     = (const float*)d_in[2];
    const float* b_p     = (const float*)d_in[3];
    float* out = (float*)d_out;

    const int B = in_sizes[0] / FLT_PER_BATCH;   // 8192

    svd_align_fused<<<B / 4, BLK, 0, stream>>>(net_in, shift_p, a_p, b_p, out);
}

// Round 6
// 165.597 us; speedup vs baseline: 1.3098x; 1.3098x over previous
//
#include <hip/hip_runtime.h>
#include <math.h>

#define NPTS 200
#define NCH  13
#define BLK  256
#define FLT_PER_BATCH (NPTS * NCH)          // 2600

// 4-byte-aligned float4 for dword-aligned (not 16B-aligned) vector loads
typedef float f4u __attribute__((ext_vector_type(4), aligned(4)));

// ---------------------------------------------------------------------------
// Kernel 1: reduce — one wave per batch, NO input LDS, direct global reads.
// Per point: 3 dword-aligned float4 loads + 1 scalar (wave span = 52 lines,
// fully consumed via L1). 16 weighted sums -> shuffle + 16x16 LDS transpose.
// ---------------------------------------------------------------------------
__global__ __launch_bounds__(BLK) void reduce_kernel(
    const float* __restrict__ net_in,   // (B, 200, 13)
    const float* __restrict__ shift_p,
    const float* __restrict__ a_p,
    const float* __restrict__ b_p,
    float* __restrict__ sums)           // (B, 16)
{
    __shared__ float s_part[4][16][20];       // per-wave 16x16 transpose (5.1 KB)

    const int tid = threadIdx.x;
    const int w   = tid >> 6;                 // wave id = local batch
    const int l   = tid & 63;
    const int b   = blockIdx.x * 4 + w;       // global batch

    const float shift = shift_p[0];
    const float aa    = a_p[0];
    const float bb    = b_p[0];

    const float* base = net_in + (size_t)b * FLT_PER_BATCH;

    float acc[16];
    #pragma unroll
    for (int k = 0; k < 16; ++k) acc[k] = 0.f;

    #pragma unroll
    for (int j = 0; j < 4; ++j) {
        const int p = l + 64 * j;             // j<3 always valid; j==3 only l<8
        if (j < 3 || l < 8) {
            const float* q = base + p * NCH;
            const f4u q0 = *(const f4u*)(q);      // w,  x1, y1, z1
            const f4u q1 = *(const f4u*)(q + 4);  // x2, y2, z2, n1x
            const f4u q2 = *(const f4u*)(q + 8);  // n1y,n1z,n2x, n2y
            const float qs = q[12];               // n2z

            float wt = aa * q0.x + bb;
            wt = fmaxf(wt, 0.f) + 1e-8f;
            const float v1x = fmaf(shift, q1.w, q0.y);
            const float v1y = fmaf(shift, q2.x, q0.z);
            const float v1z = fmaf(shift, q2.y, q0.w);
            const float v2x = fmaf(shift, q2.z, q1.x);
            const float v2y = fmaf(shift, q2.w, q1.y);
            const float v2z = fmaf(shift, qs,   q1.z);
            const float wv2x = wt * v2x, wv2y = wt * v2y, wv2z = wt * v2z;
            acc[0] += wt;
            acc[1] += wt * v1x; acc[2] += wt * v1y; acc[3] += wt * v1z;
            acc[4] += wv2x;     acc[5] += wv2y;     acc[6] += wv2z;
            acc[7]  += wv2x * v1x; acc[8]  += wv2x * v1y; acc[9]  += wv2x * v1z;
            acc[10] += wv2y * v1x; acc[11] += wv2y * v1y; acc[12] += wv2y * v1z;
            acc[13] += wv2z * v1x; acc[14] += wv2z * v1y; acc[15] += wv2z * v1z;
        }
    }

    // ---- 64 -> 16 lanes via 2 shuffle levels ----
    #pragma unroll
    for (int k = 0; k < 16; ++k) {
        acc[k] += __shfl_down(acc[k], 32, 64);
        acc[k] += __shfl_down(acc[k], 16, 64);
    }

    // ---- 16x16 transpose in wave-private LDS (same wave: no barrier) ----
    if (l < 16) {
        float4* pp = (float4*)&s_part[w][l][0];
        pp[0] = make_float4(acc[0],  acc[1],  acc[2],  acc[3]);
        pp[1] = make_float4(acc[4],  acc[5],  acc[6],  acc[7]);
        pp[2] = make_float4(acc[8],  acc[9],  acc[10], acc[11]);
        pp[3] = make_float4(acc[12], acc[13], acc[14], acc[15]);
    }
    if (l < 16) {
        float s = 0.f;
        #pragma unroll
        for (int r = 0; r < 16; ++r) s += s_part[w][r][l];
        sums[(size_t)b * 16 + l] = s;         // 16-lane coalesced store
    }
}

// ---------------------------------------------------------------------------
// Kernel 2: one thread per batch — fp32 Horn quaternion / 4x4 Jacobi (SIMT)
// ---------------------------------------------------------------------------
__global__ __launch_bounds__(BLK) void solve_kernel(
    const float* __restrict__ sums,   // (B, 16)
    float* __restrict__ Rt,           // (B, 12)
    int B)
{
    const int b = blockIdx.x * BLK + threadIdx.x;
    if (b >= B) return;

    float f[16];
    #pragma unroll
    for (int k = 0; k < 16; ++k) f[k] = sums[(size_t)b * 16 + k];

    const float W = f[0];
    const float invW = 1.0f / W;
    float v1c[3] = { f[1] * invW, f[2] * invW, f[3] * invW };
    float v2c[3] = { f[4] * invW, f[5] * invW, f[6] * invW };

    float S[3][3];
    #pragma unroll
    for (int i = 0; i < 3; ++i)
        #pragma unroll
        for (int j = 0; j < 3; ++j)
            S[i][j] = f[7 + 3 * i + j] - W * v2c[i] * v1c[j];

    const float Sxx = S[0][0], Sxy = S[0][1], Sxz = S[0][2];
    const float Syx = S[1][0], Syy = S[1][1], Syz = S[1][2];
    const float Szx = S[2][0], Szy = S[2][1], Szz = S[2][2];

    float A[4][4];
    A[0][0] = Sxx + Syy + Szz;
    A[0][1] = Syz - Szy;  A[0][2] = Szx - Sxz;  A[0][3] = Sxy - Syx;
    A[1][1] = Sxx - Syy - Szz;
    A[1][2] = Sxy + Syx;  A[1][3] = Szx + Sxz;
    A[2][2] = -Sxx + Syy - Szz;
    A[2][3] = Syz + Szy;
    A[3][3] = -Sxx - Syy + Szz;
    A[1][0] = A[0][1]; A[2][0] = A[0][2]; A[3][0] = A[0][3];
    A[2][1] = A[1][2]; A[3][1] = A[1][3]; A[3][2] = A[2][3];

    float V[4][4] = {{1,0,0,0},{0,1,0,0},{0,0,1,0},{0,0,0,1}};

    const int prs[6][2] = {{0,1},{0,2},{0,3},{1,2},{1,3},{2,3}};
    for (int sweep = 0; sweep < 6; ++sweep) {
        #pragma unroll
        for (int r = 0; r < 6; ++r) {
            const int p = prs[r][0], q = prs[r][1];
            float apq = A[p][q];
            if (apq != 0.0f) {
                float tau = (A[q][q] - A[p][p]) / (2.0f * apq);
                float t = copysignf(1.0f, tau) /
                          (fabsf(tau) + sqrtf(1.0f + tau * tau));
                float c = rsqrtf(1.0f + t * t);
                float s = t * c;
                #pragma unroll
                for (int k = 0; k < 4; ++k) {
                    float a1 = A[p][k], a2 = A[q][k];
                    A[p][k] = c * a1 - s * a2;
                    A[q][k] = s * a1 + c * a2;
                }
                #pragma unroll
                for (int k = 0; k < 4; ++k) {
                    float a1 = A[k][p], a2 = A[k][q];
                    A[k][p] = c * a1 - s * a2;
                    A[k][q] = s * a1 + c * a2;
                }
                #pragma unroll
                for (int k = 0; k < 4; ++k) {
                    float a1 = V[k][p], a2 = V[k][q];
                    V[k][p] = c * a1 - s * a2;
                    V[k][q] = s * a1 + c * a2;
                }
            }
        }
    }

    int best = 0;
    #pragma unroll
    for (int i = 1; i < 4; ++i) if (A[i][i] > A[best][best]) best = i;
    const float q0 = V[0][best], qx = V[1][best], qy = V[2][best], qz = V[3][best];

    const float R00 = q0*q0 + qx*qx - qy*qy - qz*qz;
    const float R01 = 2.0f * (qx*qy - q0*qz);
    const float R02 = 2.0f * (qx*qz + q0*qy);
    const float R10 = 2.0f * (qx*qy + q0*qz);
    const float R11 = q0*q0 - qx*qx + qy*qy - qz*qz;
    const float R12 = 2.0f * (qy*qz - q0*qx);
    const float R20 = 2.0f * (qx*qz - q0*qy);
    const float R21 = 2.0f * (qy*qz + q0*qx);
    const float R22 = q0*q0 - qx*qx - qy*qy + qz*qz;

    const float t0 = v1c[0] - (R00 * v2c[0] + R01 * v2c[1] + R02 * v2c[2]);
    const float t1 = v1c[1] - (R10 * v2c[0] + R11 * v2c[1] + R12 * v2c[2]);
    const float t2 = v1c[2] - (R20 * v2c[0] + R21 * v2c[1] + R22 * v2c[2]);

    float* o = Rt + (size_t)b * 12;
    o[0] = R00; o[1]  = R01; o[2]  = R02;
    o[3] = R10; o[4]  = R11; o[5]  = R12;
    o[6] = R20; o[7]  = R21; o[8]  = R22;
    o[9] = t0;  o[10] = t1;  o[11] = t2;
}

// ---------------------------------------------------------------------------
// Kernel 3: apply — 4 points/thread. Reads xyz2 via dword-aligned float4
// from net_in (L3-hot), writes 3 FULL float4 per thread (no partial-sector
// write amplification). No LDS, no barriers.
// ---------------------------------------------------------------------------
__global__ __launch_bounds__(BLK) void apply_kernel(
    const float* __restrict__ net_in,   // (B, 200, 13)
    const float* __restrict__ Rt,       // (B, 12)
    float* __restrict__ out,            // (B, 200, 3)
    int total)                          // B * 50
{
    const int g = blockIdx.x * BLK + threadIdx.x;   // 4-point group id
    if (g >= total) return;
    const int b = g / 50;
    const int q = g - b * 50;                       // quad index in batch

    const float* r = Rt + (size_t)b * 12;
    const float R00 = r[0], R01 = r[1], R02 = r[2];
    const float R10 = r[3], R11 = r[4], R12 = r[5];
    const float R20 = r[6], R21 = r[7], R22 = r[8];
    const float t0  = r[9], t1  = r[10], t2 = r[11];

    const float* base = net_in + (size_t)b * FLT_PER_BATCH + (q * 4) * NCH;
    float nx[4], ny[4], nz[4];
    #pragma unroll
    for (int i = 0; i < 4; ++i) {
        const f4u v = *(const f4u*)(base + i * NCH + 4);   // x2,y2,z2,(n1x)
        nx[i] = R00 * v.x + R01 * v.y + R02 * v.z + t0;
        ny[i] = R10 * v.x + R11 * v.y + R12 * v.z + t1;
        nz[i] = R20 * v.x + R21 * v.y + R22 * v.z + t2;
    }

    float4* p = (float4*)(out + (size_t)b * (NPTS * 3)) + q * 3;  // 16B aligned
    p[0] = make_float4(nx[0], ny[0], nz[0], nx[1]);
    p[1] = make_float4(ny[1], nz[1], nx[2], ny[2]);
    p[2] = make_float4(nz[2], nx[3], ny[3], nz[3]);
}

extern "C" void kernel_launch(void* const* d_in, const int* in_sizes, int n_in,
                              void* d_out, int out_size, void* d_ws, size_t ws_size,
                              hipStream_t stream) {
    const float* net_in  = (const float*)d_in[0];
    const float* shift_p = (const float*)d_in[1];
    const float* a_p     = (const float*)d_in[2];
    const float* b_p     = (const float*)d_in[3];
    float* out = (float*)d_out;

    const int B = in_sizes[0] / FLT_PER_BATCH;   // 8192

    float* sums = (float*)d_ws;                  // B * 16 floats
    float* Rt   = sums + (size_t)B * 16;         // B * 12 floats

    reduce_kernel<<<B / 4, BLK, 0, stream>>>(net_in, shift_p, a_p, b_p, sums);
    solve_kernel<<<(B + BLK - 1) / BLK, BLK, 0, stream>>>(sums, Rt, B);
    apply_kernel<<<(B * 50 + BLK - 1) / BLK, BLK, 0, stream>>>(net_in, Rt, out, B * 50);
}